// Round 4
// baseline (1246.507 us; speedup 1.0000x reference)
//
#include <hip/hip_runtime.h>
#include <hip/hip_bf16.h>
#include <math.h>

#define NB 8
#define NT 2048
#define NC 768
#define ROWS (NB*NT)   // 16384

typedef __attribute__((ext_vector_type(8))) short s8v;   // 8 bf16 (4 VGPRs)
typedef __attribute__((ext_vector_type(4))) float f4v;   // 4 fp32 acc

__device__ __forceinline__ unsigned short f2b(float f) {  // fp32->bf16 RNE
    unsigned u = __builtin_bit_cast(unsigned, f);
    return (unsigned short)((u + 0x7FFFu + ((u >> 16) & 1u)) >> 16);
}

// async global->LDS, 16B per lane, LDS dest = wave-uniform base + lane*16
__device__ __forceinline__ void gl2lds16(const void* g, void* l) {
    __builtin_amdgcn_global_load_lds(
        (const __attribute__((address_space(1))) unsigned int*)g,
        (__attribute__((address_space(3))) unsigned int*)l,
        16, 0, 0);
}

// LDS tile: 128 rows x 32 k (bf16), row stride 32 ushorts (64B), 16B chunks
// XOR-swizzled by (row>>1)&3; swizzle realized by permuting the GLOBAL source
// chunk per lane (LDS slot order is fixed by lane id for global_load_lds).
__device__ __forceinline__ void stage_async(ushort* L, const ushort* G, int ld,
                                            int r0, int k0, int w, int lane) {
#pragma unroll
    for (int i = 0; i < 2; i++) {
        int p = i * 256 + w * 64 + lane;      // LDS chunk slot (16B units)
        int row = p >> 2, cc = p & 3;
        int kc = cc ^ ((row >> 1) & 3);       // which global k-chunk lands here
        gl2lds16(G + (long)(r0 + row) * ld + k0 + kc * 8,
                 &L[(i * 256 + w * 64) * 8]);
    }
}

// fp32 source -> bf16 swizzled staging (VALU path; GLU A-operand only)
__device__ __forceinline__ void stage_cvt(ushort* L, const float* G, int ld,
                                          int r0, int k0, int t) {
#pragma unroll
    for (int p = 0; p < 4; p++) {
        int e = p * 256 + t;
        int row = e >> 3, kc = (e & 7) * 4;
        float4 v = *(const float4*)(G + (long)(r0 + row) * ld + k0 + kc);
        ushort4 o;
        o.x = f2b(v.x); o.y = f2b(v.y); o.z = f2b(v.z); o.w = f2b(v.w);
        int c = (kc >> 3) ^ ((row >> 1) & 3);
        *(ushort4*)&L[row * 32 + c * 8 + (kc & 7)] = o;
    }
}

// ---------------- MFMA GEMM: C = A@B (+bias)(+resid)(gelu) ----------------
// AMODE: 0=bf16 [M,K] async; 2=fp32 [M,K] convert
// B always bf16 [N,K] (outer-major) async. 128x128 tile, 4 waves.
// EPI: 0=bf16 out; 2=gelu->bf16; 3=fp32 resid in-place; 4=resid + bf16 dual; 5=fp32 out
template<int AMODE, int EPI, bool HASBIAS>
__global__ __launch_bounds__(256) void gemm_mfma(
    const void* __restrict__ A, const ushort* __restrict__ Bt,
    float* __restrict__ Cf, ushort* __restrict__ Cb,
    int M, int N, int K, int lda, int ldb, int ldc,
    long sA, long sB, long sC, const float* __restrict__ bias)
{
    int z = blockIdx.z;
    const void* Az = (AMODE == 2) ? (const void*)((const float*)A + (long)z * sA)
                                  : (const void*)((const ushort*)A + (long)z * sA);
    const ushort* Bz = Bt + (long)z * sB;
    float*  Cfz = Cf ? Cf + (long)z * sC : nullptr;
    ushort* Cbz = Cb ? Cb + (long)z * sC : nullptr;

    int m0 = blockIdx.y * 128, n0 = blockIdx.x * 128;
    __shared__ alignas(16) ushort Al[4096];
    __shared__ alignas(16) ushort Bl[4096];
    int t = threadIdx.x;
    int lane = t & 63, w = t >> 6;
    int wm = (w >> 1) * 64, wn = (w & 1) * 64;
    int fr = lane & 15, q = lane >> 4;

    f4v acc[4][4];
#pragma unroll
    for (int i = 0; i < 4; i++)
#pragma unroll
        for (int j = 0; j < 4; j++) acc[i][j] = (f4v)(0.0f);

    for (int k0 = 0; k0 < K; k0 += 32) {
        if (AMODE == 0) stage_async(Al, (const ushort*)Az, lda, m0, k0, w, lane);
        else            stage_cvt(Al, (const float*)Az, lda, m0, k0, t);
        stage_async(Bl, Bz, ldb, n0, k0, w, lane);
        __syncthreads();
        s8v af[4], bf[4];
#pragma unroll
        for (int ti = 0; ti < 4; ti++) {
            int r = wm + ti * 16 + fr;
            af[ti] = *(const s8v*)&Al[r * 32 + ((q ^ ((r >> 1) & 3)) << 3)];
        }
#pragma unroll
        for (int tj = 0; tj < 4; tj++) {
            int r = wn + tj * 16 + fr;
            bf[tj] = *(const s8v*)&Bl[r * 32 + ((q ^ ((r >> 1) & 3)) << 3)];
        }
#pragma unroll
        for (int ti = 0; ti < 4; ti++)
#pragma unroll
            for (int tj = 0; tj < 4; tj++)
                acc[ti][tj] = __builtin_amdgcn_mfma_f32_16x16x32_bf16(
                    af[ti], bf[tj], acc[ti][tj], 0, 0, 0);
        __syncthreads();
    }

    int cr0 = q * 4;  // C/D: col = lane&15, row = (lane>>4)*4 + reg
#pragma unroll
    for (int ti = 0; ti < 4; ti++) {
#pragma unroll
        for (int tj = 0; tj < 4; tj++) {
            int n = n0 + wn + tj * 16 + fr;
            float bv = HASBIAS ? bias[n] : 0.0f;
#pragma unroll
            for (int r = 0; r < 4; r++) {
                int m = m0 + wm + ti * 16 + cr0 + r;
                long idx = (long)m * ldc + n;
                float v = acc[ti][tj][r] + bv;
                if (EPI == 2) {
                    v = 0.5f * v * (1.0f + erff(v * 0.70710678118654752440f));
                    Cbz[idx] = f2b(v);
                } else if (EPI == 0) {
                    Cbz[idx] = f2b(v);
                } else if (EPI == 5) {
                    Cfz[idx] = v;
                } else {  // 3, 4: fp32 residual in place
                    v += Cfz[idx];
                    Cfz[idx] = v;
                    if (EPI == 4) Cbz[idx] = f2b(v);
                }
            }
        }
    }
}

// ---------------- fused GLU GEMM: out = (A@Wv+bv)*sigmoid(A@Wg+bg)*s ----------------
// B = W^T bf16 [2Nh, K]: value rows [0,Nh), gate rows [Nh,2Nh). out bf16 [M,Nh].
template<bool HAS_S, bool AF32>
__global__ __launch_bounds__(256) void gemm_glu_mfma(
    const void* __restrict__ A, const ushort* __restrict__ Bt,
    ushort* __restrict__ Cb, int M, int Nh, int K, int lda,
    const float* __restrict__ bias, const float* __restrict__ s, int bofs)
{
    int m0 = blockIdx.y * 128, n0 = blockIdx.x * 128;
    __shared__ alignas(16) ushort Al[4096];
    __shared__ alignas(16) ushort B1[4096];
    __shared__ alignas(16) ushort B2[4096];
    int t = threadIdx.x;
    int lane = t & 63, w = t >> 6;
    int wm = (w >> 1) * 64, wn = (w & 1) * 64;
    int fr = lane & 15, q = lane >> 4;

    f4v acc1[4][4], acc2[4][4];
#pragma unroll
    for (int i = 0; i < 4; i++)
#pragma unroll
        for (int j = 0; j < 4; j++) { acc1[i][j] = (f4v)(0.0f); acc2[i][j] = (f4v)(0.0f); }

    for (int k0 = 0; k0 < K; k0 += 32) {
        if (AF32) stage_cvt(Al, (const float*)A, lda, m0, k0, t);
        else      stage_async(Al, (const ushort*)A, lda, m0, k0, w, lane);
        stage_async(B1, Bt, K, n0, k0, w, lane);
        stage_async(B2, Bt, K, Nh + n0, k0, w, lane);
        __syncthreads();
        s8v af[4], b1f[4], b2f[4];
#pragma unroll
        for (int ti = 0; ti < 4; ti++) {
            int r = wm + ti * 16 + fr;
            af[ti] = *(const s8v*)&Al[r * 32 + ((q ^ ((r >> 1) & 3)) << 3)];
        }
#pragma unroll
        for (int tj = 0; tj < 4; tj++) {
            int r = wn + tj * 16 + fr;
            int o = r * 32 + ((q ^ ((r >> 1) & 3)) << 3);
            b1f[tj] = *(const s8v*)&B1[o];
            b2f[tj] = *(const s8v*)&B2[o];
        }
#pragma unroll
        for (int ti = 0; ti < 4; ti++)
#pragma unroll
            for (int tj = 0; tj < 4; tj++) {
                acc1[ti][tj] = __builtin_amdgcn_mfma_f32_16x16x32_bf16(af[ti], b1f[tj], acc1[ti][tj], 0, 0, 0);
                acc2[ti][tj] = __builtin_amdgcn_mfma_f32_16x16x32_bf16(af[ti], b2f[tj], acc2[ti][tj], 0, 0, 0);
            }
        __syncthreads();
    }

    int cr0 = q * 4;
#pragma unroll
    for (int ti = 0; ti < 4; ti++) {
        int bb = ((m0 + wm + ti * 16 + cr0) >> 11) + bofs;   // batch = row/2048
#pragma unroll
        for (int tj = 0; tj < 4; tj++) {
            int n = n0 + wn + tj * 16 + fr;
            float bv = bias[n], bg = bias[Nh + n];
            float sv = HAS_S ? s[(long)bb * Nh + n] : 1.0f;
#pragma unroll
            for (int r = 0; r < 4; r++) {
                int m = m0 + wm + ti * 16 + cr0 + r;
                float vv = acc1[ti][tj][r] + bv;
                float gg = acc2[ti][tj][r] + bg;
                float a = vv * (1.0f / (1.0f + expf(-gg)));
                if (HAS_S) a *= sv;
                Cb[(long)m * Nh + n] = f2b(a);
            }
        }
    }
}

// ---------------- transpose: src [R,C] (batched) -> dst bf16 [C,R] ----------------
template<bool SRC_F32>
__global__ __launch_bounds__(256) void transpose_kernel(const void* __restrict__ src,
                                                        ushort* __restrict__ dst,
                                                        int R, int C, long sS, long sD) {
    int z = blockIdx.z;
    const void* S = SRC_F32 ? (const void*)((const float*)src + (long)z * sS)
                            : (const void*)((const ushort*)src + (long)z * sS);
    ushort* D = dst + (long)z * sD;
    int r0 = blockIdx.y * 64, c0 = blockIdx.x * 64;
    __shared__ ushort T[64][68];
    int t = threadIdx.x;
#pragma unroll
    for (int p = 0; p < 4; p++) {
        int e = p * 256 + t;
        int row = e >> 4, cc = (e & 15) * 4;
        ushort4 v;
        if (SRC_F32) {
            float4 f = *(const float4*)((const float*)S + (long)(r0 + row) * C + c0 + cc);
            v.x = f2b(f.x); v.y = f2b(f.y); v.z = f2b(f.z); v.w = f2b(f.w);
        } else {
            v = *(const ushort4*)((const ushort*)S + (long)(r0 + row) * C + c0 + cc);
        }
        *(ushort4*)&T[row][cc] = v;
    }
    __syncthreads();
#pragma unroll
    for (int p = 0; p < 4; p++) {
        int e = p * 256 + t;
        int crow = e >> 4, rr = (e & 15) * 4;
        ushort4 o;
        o.x = T[rr + 0][crow]; o.y = T[rr + 1][crow];
        o.z = T[rr + 2][crow]; o.w = T[rr + 3][crow];
        *(ushort4*)&D[(long)(c0 + crow) * R + r0 + rr] = o;
    }
}

// ---------------- weight cast+transpose: Wt[n*K+k] = bf16(W[k*N+n]) ----------------
__global__ __launch_bounds__(256) void castT_kernel(const float* __restrict__ W,
                                                    ushort* __restrict__ Wt, int K, int N) {
    int k = blockIdx.x * 64 + (threadIdx.x & 63);
    int n = blockIdx.y * 4 + (threadIdx.x >> 6);
    Wt[(long)n * K + k] = f2b(W[(long)k * N + n]);
}

// ---------------- LayerNorm, one block per row of 768; fp32 or bf16 out ----------------
template<bool BF16OUT>
__global__ __launch_bounds__(256) void ln_kernel(const float* __restrict__ x,
                                                 const float* __restrict__ g,
                                                 const float* __restrict__ b,
                                                 void* __restrict__ outv) {
    int row = blockIdx.x;
    const float* xr = x + (long)row * NC;
    int t = threadIdx.x;
    float v0 = xr[t], v1 = xr[t + 256], v2 = xr[t + 512];
    float s = v0 + v1 + v2;
    float s2 = v0 * v0 + v1 * v1 + v2 * v2;
    for (int off = 32; off > 0; off >>= 1) {
        s  += __shfl_down(s, off, 64);
        s2 += __shfl_down(s2, off, 64);
    }
    __shared__ float ls[4], ls2[4];
    int wid = t >> 6, lane = t & 63;
    if (lane == 0) { ls[wid] = s; ls2[wid] = s2; }
    __syncthreads();
    if (t == 0) {
        float ts = ls[0] + ls[1] + ls[2] + ls[3];
        float ts2 = ls2[0] + ls2[1] + ls2[2] + ls2[3];
        float mu = ts * (1.0f / NC);
        float var = ts2 * (1.0f / NC) - mu * mu;
        ls[0] = mu;
        ls2[0] = 1.0f / sqrtf(var + 1e-6f);
    }
    __syncthreads();
    float mu = ls[0], r = ls2[0];
#pragma unroll
    for (int i = 0; i < 3; i++) {
        int c = t + i * 256;
        float vv = (i == 0 ? v0 : (i == 1 ? v1 : v2));
        float o = (vv - mu) * r * g[c] + b[c];
        if (BF16OUT) ((ushort*)outv)[(long)row * NC + c] = f2b(o);
        else         ((float*)outv)[(long)row * NC + c] = o;
    }
}

// ---------------- style vectors (fp32): s1[8,384] | s2[8,384] | ss[8,1536] ----------------
__global__ __launch_bounds__(256) void svec_kernel(const float* __restrict__ w,
                                                   const float* __restrict__ s1W, const float* __restrict__ s1b,
                                                   const float* __restrict__ s2W, const float* __restrict__ s2b,
                                                   const float* __restrict__ ssW, const float* __restrict__ ssb,
                                                   float* __restrict__ sout) {
    int gid = blockIdx.x * 256 + threadIdx.x;   // 0..18431
    int bb = gid / 2304;
    int r  = gid % 2304;
    const float* w0 = w + (long)bb * 1024;
    const float* w1 = w0 + 512;
    float acc = 0.f;
    if (r < 384) {
        for (int k = 0; k < 512; k++) acc += w0[k] * s1W[k * 384 + r];
        sout[bb * 384 + r] = acc + s1b[r];
    } else if (r < 768) {
        int c = r - 384;
        for (int k = 0; k < 512; k++) acc += w0[k] * s2W[k * 384 + c];
        sout[3072 + bb * 384 + c] = acc + s2b[c];
    } else {
        int c = r - 768;
        for (int k = 0; k < 512; k++) acc += w1[k] * ssW[k * 1536 + c];
        sout[6144 + bb * 1536 + c] = acc + ssb[c];
    }
}

extern "C" void kernel_launch(void* const* d_in, const int* in_sizes, int n_in,
                              void* d_out, int out_size, void* d_ws, size_t ws_size,
                              hipStream_t stream) {
    const float* x     = (const float*)d_in[0];
    const float* w     = (const float*)d_in[1];
    const float* ln1_g = (const float*)d_in[2];
    const float* ln1_b = (const float*)d_in[3];
    const float* ln2_g = (const float*)d_in[4];
    const float* ln2_b = (const float*)d_in[5];
    const float* g1_W  = (const float*)d_in[6];
    const float* g1_b  = (const float*)d_in[7];
    const float* s1_W  = (const float*)d_in[8];
    const float* s1_b  = (const float*)d_in[9];
    const float* m1_W  = (const float*)d_in[10];
    const float* m1_b  = (const float*)d_in[11];
    const float* g2_W  = (const float*)d_in[12];
    const float* g2_b  = (const float*)d_in[13];
    const float* s2_W  = (const float*)d_in[14];
    const float* s2_b  = (const float*)d_in[15];
    const float* m2_W  = (const float*)d_in[16];
    const float* m2_b  = (const float*)d_in[17];
    const float* gs_W  = (const float*)d_in[18];
    const float* gs_b  = (const float*)d_in[19];
    const float* ss_W  = (const float*)d_in[20];
    const float* ss_b  = (const float*)d_in[21];
    const float* ms_W  = (const float*)d_in[22];
    const float* ms_b  = (const float*)d_in[23];
    const float* r1_W  = (const float*)d_in[24];
    const float* r1_b  = (const float*)d_in[25];
    const float* r2_W  = (const float*)d_in[26];
    const float* r2_b  = (const float*)d_in[27];
    float* out = (float*)d_out;
    char* ws = (char*)d_ws;

    // ---- ws layout (74,784,768 B; identical footprint to the proven R3 layout) ----
    float*  XLN = (float*)ws;                 // [16384,768] f32: xln -> x2 -> x3, 50,331,648 B
    ushort* A1b = (ushort*)(ws + 50331648);   // 12,582,912 B: a2 -> a1 -> H1T[8,384,2048] -> ar
    ushort* g1t = (ushort*)(ws + 62914560);   // W^T bf16 pool, 11,796,480 B
    ushort* g2t = g1t + 589824;
    ushort* m1t = g2t + 589824;
    ushort* m2t = m1t + 147456;
    ushort* gst = m2t + 147456;
    ushort* mst = gst + 2359296;
    ushort* r1t = mst + 1179648;
    ushort* r2t = r1t + 589824;
    float*  SV  = (float*)(ws + 74711040);    // 18432 f32
    ushort* H1T = A1b;                        // [8,384,2048] alias (a1 consumed)

    // ---- d_out as scratch (50,331,648 B) ----
    // phase1: H1b [0:12.58M) | H2b [12.58:25.17M) | XLNT [25.17:50.33M)
    // after T2: MIXT [0:4.72M) overwrites H1b
    // phase2 (per chunk): X3b [0:25.17M) | X2LNb [25.17:31.46M) | ASb [37.75:50.33M)
    ushort* H1b   = (ushort*)d_out;
    ushort* H2b   = (ushort*)((char*)d_out + 12582912);
    ushort* XLNT  = (ushort*)((char*)d_out + 25165824);  // [8,768,2048] bf16
    ushort* MIXT  = (ushort*)d_out;                      // [8,768,384] bf16
    ushort* X3b   = (ushort*)d_out;                      // [16384,768] bf16
    ushort* X2LNb = (ushort*)((char*)d_out + 25165824);  // [4096,768] bf16 chunk
    ushort* ASb   = (ushort*)((char*)d_out + 37748736);  // [4096,1536] bf16 chunk

    // 0. weight casts + style vectors + LN1
    castT_kernel<<<dim3(12, 192), 256, 0, stream>>>(g1_W, g1t, 768, 768);
    castT_kernel<<<dim3(12, 192), 256, 0, stream>>>(g2_W, g2t, 768, 768);
    castT_kernel<<<dim3(6,  96),  256, 0, stream>>>(m1_W, m1t, 384, 384);
    castT_kernel<<<dim3(6,  96),  256, 0, stream>>>(m2_W, m2t, 384, 384);
    castT_kernel<<<dim3(12, 768), 256, 0, stream>>>(gs_W, gst, 768, 3072);
    castT_kernel<<<dim3(24, 192), 256, 0, stream>>>(ms_W, mst, 1536, 768);
    castT_kernel<<<dim3(12, 192), 256, 0, stream>>>(r1_W, r1t, 768, 768);
    castT_kernel<<<dim3(6,  192), 256, 0, stream>>>(r2_W, r2t, 384, 768);
    svec_kernel<<<72, 256, 0, stream>>>(w, s1_W, s1_b, s2_W, s2_b, ss_W, ss_b, SV);
    ln_kernel<false><<<ROWS, 256, 0, stream>>>(x, ln1_g, ln1_b, XLN);
    // T1: XLNT[b] = bf16(xln[b]^T)
    transpose_kernel<true><<<dim3(12, 32, NB), 256, 0, stream>>>(
        XLN, XLNT, 2048, 768, (long)2048 * 768, (long)768 * 2048);

    // 5. a2 = glu(xln@g2_W)*s2 -> A1b ; 6. h2 = a2@m2_W -> H2b
    gemm_glu_mfma<true, true><<<dim3(3, 128), 256, 0, stream>>>(
        XLN, g2t, A1b, ROWS, 384, 768, 768, g2_b, SV + 3072, 0);
    gemm_mfma<0, 0, true><<<dim3(3, 128), 256, 0, stream>>>(
        A1b, m2t, nullptr, H2b, ROWS, 384, 384, 384, 384, 384, 0, 0, 0, m2_b);
    // 3. a1 -> A1b ; 4. h1 = a1@m1_W -> H1b
    gemm_glu_mfma<true, true><<<dim3(3, 128), 256, 0, stream>>>(
        XLN, g1t, A1b, ROWS, 384, 768, 768, g1_b, SV, 0);
    gemm_mfma<0, 0, true><<<dim3(3, 128), 256, 0, stream>>>(
        A1b, m1t, nullptr, H1b, ROWS, 384, 384, 384, 384, 384, 0, 0, 0, m1_b);
    // T2: H1T[b] = h1[b]^T  (into freed A1b slot)
    transpose_kernel<false><<<dim3(6, 32, NB), 256, 0, stream>>>(
        H1b, H1T, 2048, 384, (long)2048 * 384, (long)384 * 2048);
    // 7. mixT[b] = gelu(xlnT[b] @ h1T[b]^T)  -> MIXT  (M=768,N=384,K=2048)
    gemm_mfma<0, 2, false><<<dim3(3, 6, NB), 256, 0, stream>>>(
        XLNT, H1T, nullptr, MIXT, 768, 384, 2048, 2048, 2048, 384,
        (long)768 * 2048, (long)384 * 2048, (long)768 * 384, nullptr);
    // 8. x2 = xln + h2[b] @ mixT[b]^T  (fp32 in-place; M=2048,N=768,K=384)
    gemm_mfma<0, 3, false><<<dim3(6, 16, NB), 256, 0, stream>>>(
        H2b, MIXT, XLN, nullptr, 2048, 768, 384, 384, 384, 768,
        (long)2048 * 384, (long)768 * 384, (long)2048 * 768, nullptr);
    // 9-11. style branch, 4 chunks of 4096 rows (2 batches each)
    for (int ch = 0; ch < 4; ch++) {
        float*  XLNc = XLN + (long)ch * 4096 * 768;
        ushort* X3c  = X3b + (long)ch * 4096 * 768;
        ln_kernel<true><<<4096, 256, 0, stream>>>(XLNc, ln2_g, ln2_b, X2LNb);
        gemm_glu_mfma<true, false><<<dim3(12, 32), 256, 0, stream>>>(
            X2LNb, gst, ASb, 4096, 1536, 768, 768, gs_b, SV + 6144, ch * 2);
        gemm_mfma<0, 4, true><<<dim3(6, 32), 256, 0, stream>>>(
            ASb, mst, XLNc, X3c, 4096, 768, 1536, 1536, 1536, 768, 0, 0, 0, ms_b);
    }
    // 12. ar = glu(x3@r1_W) -> A1b
    gemm_glu_mfma<false, false><<<dim3(3, 128), 256, 0, stream>>>(
        X3b, r1t, A1b, ROWS, 384, 768, 768, r1_b, nullptr, 0);
    // 13. out = ar@r2_W + r2_b (fp32, overwrites all d_out scratch last)
    gemm_mfma<0, 5, true><<<dim3(6, 128), 256, 0, stream>>>(
        A1b, r2t, out, nullptr, ROWS, 768, 384, 384, 384, 768, 0, 0, 0, r2_b);
}

// Round 5
// 876.515 us; speedup vs baseline: 1.4221x; 1.4221x over previous
//
#include <hip/hip_runtime.h>
#include <hip/hip_bf16.h>
#include <math.h>

#define NB 8
#define NT 2048
#define NC 768
#define ROWS (NB*NT)   // 16384

typedef __attribute__((ext_vector_type(8))) short s8v;   // 8 bf16 (4 VGPRs)
typedef __attribute__((ext_vector_type(4))) float f4v;   // 4 fp32 acc

__device__ __forceinline__ unsigned short f2b(float f) {  // fp32->bf16 RNE
    unsigned u = __builtin_bit_cast(unsigned, f);
    return (unsigned short)((u + 0x7FFFu + ((u >> 16) & 1u)) >> 16);
}

// LDS tile: R rows x 32 k (bf16), row stride 32 ushorts, 16B chunks,
// XOR-swizzled by (row>>1)&3. VGPR staging (compiler can prefetch across iters).
template<int R>
__device__ __forceinline__ void stage_b16(ushort* __restrict__ L, const ushort* __restrict__ G,
                                          int ld, int r0, int k0, int t) {
#pragma unroll
    for (int i = 0; i < R / 64; i++) {
        int e = i * 256 + t;                  // 16B chunk id
        int row = e >> 2, kc = (e & 3) * 8;
        uint4 v = *(const uint4*)(G + (long)(r0 + row) * ld + k0 + kc);
        int c = (kc >> 3) ^ ((row >> 1) & 3);
        *(uint4*)&L[row * 32 + c * 8] = v;
    }
}

template<int R>
__device__ __forceinline__ void stage_f32(ushort* __restrict__ L, const float* __restrict__ G,
                                          int ld, int r0, int k0, int t) {
#pragma unroll
    for (int i = 0; i < R / 32; i++) {
        int e = i * 256 + t;                  // float4 chunk id
        int row = e >> 3, kc = (e & 7) * 4;
        float4 v = *(const float4*)(G + (long)(r0 + row) * ld + k0 + kc);
        ushort4 o;
        o.x = f2b(v.x); o.y = f2b(v.y); o.z = f2b(v.z); o.w = f2b(v.w);
        int c = (kc >> 3) ^ ((row >> 1) & 3);
        *(ushort4*)&L[row * 32 + c * 8 + (kc & 7)] = o;
    }
}

// ---------------- MFMA GEMM: C = A@B^T-layout (+bias)(+resid) ----------------
// A bf16 [M,K]; B bf16 [N,K] outer-major. Tile 128xTN, 4 waves.
// EPI: 0=bf16+bias; 3=f32 resid in-place; 4=resid f32 + dual bf16; 5=f32+bias; 6=atomic f32
template<int TN, int EPI, bool HASBIAS, bool SPLITK>
__global__ __launch_bounds__(256) void gemm_mfma(
    const ushort* __restrict__ A, const ushort* __restrict__ Bt,
    float* __restrict__ Cf, ushort* __restrict__ Cb,
    int M, int N, int K, int lda, int ldb, int ldc,
    long sA, long sB, long sC, const float* __restrict__ bias)
{
    constexpr int WM = (TN == 128) ? 64 : 32;
    constexpr int TI = WM / 16;               // 4 or 2
    int zz = blockIdx.z;
    int z  = SPLITK ? (zz >> 2) : zz;
    int kb = SPLITK ? (zz & 3) * (K >> 2) : 0;
    int ke = SPLITK ? kb + (K >> 2) : K;
    const ushort* Az = A + (long)z * sA;
    const ushort* Bz = Bt + (long)z * sB;
    float*  Cfz = Cf ? Cf + (long)z * sC : nullptr;
    ushort* Cbz = Cb ? Cb + (long)z * sC : nullptr;

    int m0 = blockIdx.y * 128, n0 = blockIdx.x * TN;
    __shared__ alignas(16) ushort Al[4096];
    __shared__ alignas(16) ushort Bl[TN * 32];
    int t = threadIdx.x;
    int lane = t & 63, w = t >> 6;
    int wm = (TN == 128) ? (w >> 1) * 64 : w * 32;
    int wn = (TN == 128) ? (w & 1) * 64 : 0;
    int fr = lane & 15, q = lane >> 4;

    f4v acc[TI][4];
#pragma unroll
    for (int i = 0; i < TI; i++)
#pragma unroll
        for (int j = 0; j < 4; j++) acc[i][j] = (f4v)(0.0f);

    for (int k0 = kb; k0 < ke; k0 += 32) {
        stage_b16<128>(Al, Az, lda, m0, k0, t);
        stage_b16<TN>(Bl, Bz, ldb, n0, k0, t);
        __syncthreads();
        s8v af[TI], bf[4];
#pragma unroll
        for (int ti = 0; ti < TI; ti++) {
            int r = wm + ti * 16 + fr;
            af[ti] = *(const s8v*)&Al[r * 32 + ((q ^ ((r >> 1) & 3)) << 3)];
        }
#pragma unroll
        for (int tj = 0; tj < 4; tj++) {
            int r = wn + tj * 16 + fr;
            bf[tj] = *(const s8v*)&Bl[r * 32 + ((q ^ ((r >> 1) & 3)) << 3)];
        }
#pragma unroll
        for (int ti = 0; ti < TI; ti++)
#pragma unroll
            for (int tj = 0; tj < 4; tj++)
                acc[ti][tj] = __builtin_amdgcn_mfma_f32_16x16x32_bf16(
                    af[ti], bf[tj], acc[ti][tj], 0, 0, 0);
        __syncthreads();
    }

    int cr0 = q * 4;  // C/D: col = lane&15, row = (lane>>4)*4 + reg
#pragma unroll
    for (int ti = 0; ti < TI; ti++) {
#pragma unroll
        for (int tj = 0; tj < 4; tj++) {
            int n = n0 + wn + tj * 16 + fr;
            float bv = HASBIAS ? bias[n] : 0.0f;
#pragma unroll
            for (int r = 0; r < 4; r++) {
                int m = m0 + wm + ti * 16 + cr0 + r;
                long idx = (long)m * ldc + n;
                float v = acc[ti][tj][r] + bv;
                if (EPI == 0) {
                    Cbz[idx] = f2b(v);
                } else if (EPI == 5) {
                    Cfz[idx] = v;
                } else if (EPI == 6) {
                    __hip_atomic_fetch_add(&Cfz[idx], v, __ATOMIC_RELAXED,
                                           __HIP_MEMORY_SCOPE_AGENT);
                } else {  // 3, 4
                    v += Cfz[idx];
                    Cfz[idx] = v;
                    if (EPI == 4) Cbz[idx] = f2b(v);
                }
            }
        }
    }
}

// ---------------- fused GLU GEMM: out = (A@Wv+bv)*sigmoid(A@Wg+bg)*s ----------------
// B = W^T bf16 [2Nh, K]. grid.z selects {Bt,C,bias,s} pair (merged dispatches).
template<int TN, bool HAS_S, bool AF32>
__global__ __launch_bounds__(256) void gemm_glu_mfma(
    const void* __restrict__ A,
    const ushort* __restrict__ Bt0, const ushort* __restrict__ Bt1,
    ushort* __restrict__ C0, ushort* __restrict__ C1,
    int M, int Nh, int K, int lda,
    const float* __restrict__ bias0, const float* __restrict__ bias1,
    const float* __restrict__ s0, const float* __restrict__ s1, int bofs)
{
    constexpr int WM = (TN == 128) ? 64 : 32;
    constexpr int TI = WM / 16;
    int z = blockIdx.z;
    const ushort* Bt = z ? Bt1 : Bt0;
    ushort* Cb = z ? C1 : C0;
    const float* bias = z ? bias1 : bias0;
    const float* s = z ? s1 : s0;

    int m0 = blockIdx.y * 128, n0 = blockIdx.x * TN;
    __shared__ alignas(16) ushort Al[4096];
    __shared__ alignas(16) ushort B1[TN * 32];
    __shared__ alignas(16) ushort B2[TN * 32];
    int t = threadIdx.x;
    int lane = t & 63, w = t >> 6;
    int wm = (TN == 128) ? (w >> 1) * 64 : w * 32;
    int wn = (TN == 128) ? (w & 1) * 64 : 0;
    int fr = lane & 15, q = lane >> 4;

    f4v acc1[TI][4], acc2[TI][4];
#pragma unroll
    for (int i = 0; i < TI; i++)
#pragma unroll
        for (int j = 0; j < 4; j++) { acc1[i][j] = (f4v)(0.0f); acc2[i][j] = (f4v)(0.0f); }

    for (int k0 = 0; k0 < K; k0 += 32) {
        if (AF32) stage_f32<128>(Al, (const float*)A, lda, m0, k0, t);
        else      stage_b16<128>(Al, (const ushort*)A, lda, m0, k0, t);
        stage_b16<TN>(B1, Bt, K, n0, k0, t);
        stage_b16<TN>(B2, Bt, K, Nh + n0, k0, t);
        __syncthreads();
        s8v af[TI], b1f[4], b2f[4];
#pragma unroll
        for (int ti = 0; ti < TI; ti++) {
            int r = wm + ti * 16 + fr;
            af[ti] = *(const s8v*)&Al[r * 32 + ((q ^ ((r >> 1) & 3)) << 3)];
        }
#pragma unroll
        for (int tj = 0; tj < 4; tj++) {
            int r = wn + tj * 16 + fr;
            int o = r * 32 + ((q ^ ((r >> 1) & 3)) << 3);
            b1f[tj] = *(const s8v*)&B1[o];
            b2f[tj] = *(const s8v*)&B2[o];
        }
#pragma unroll
        for (int ti = 0; ti < TI; ti++)
#pragma unroll
            for (int tj = 0; tj < 4; tj++) {
                acc1[ti][tj] = __builtin_amdgcn_mfma_f32_16x16x32_bf16(af[ti], b1f[tj], acc1[ti][tj], 0, 0, 0);
                acc2[ti][tj] = __builtin_amdgcn_mfma_f32_16x16x32_bf16(af[ti], b2f[tj], acc2[ti][tj], 0, 0, 0);
            }
        __syncthreads();
    }

    int cr0 = q * 4;
#pragma unroll
    for (int ti = 0; ti < TI; ti++) {
        int bb = ((m0 + wm + ti * 16 + cr0) >> 11) + bofs;   // batch = row/2048
#pragma unroll
        for (int tj = 0; tj < 4; tj++) {
            int n = n0 + wn + tj * 16 + fr;
            float bv = bias[n], bg = bias[Nh + n];
            float sv = HAS_S ? s[(long)bb * Nh + n] : 1.0f;
#pragma unroll
            for (int r = 0; r < 4; r++) {
                int m = m0 + wm + ti * 16 + cr0 + r;
                float vv = acc1[ti][tj][r] + bv;
                float gg = acc2[ti][tj][r] + bg;
                float a = vv * (1.0f / (1.0f + expf(-gg)));
                if (HAS_S) a *= sv;
                Cb[(long)m * Nh + n] = f2b(a);
            }
        }
    }
}

// ---------------- gelu + cast fp32 -> bf16 (elementwise, float4) ----------------
__global__ __launch_bounds__(256) void gelu_cast_kernel(const float* __restrict__ in,
                                                        ushort* __restrict__ out) {
    int i4 = (blockIdx.x * 256 + threadIdx.x) * 4;
    float4 v = *(const float4*)(in + i4);
    ushort4 o;
    o.x = f2b(0.5f * v.x * (1.0f + erff(v.x * 0.70710678118654752440f)));
    o.y = f2b(0.5f * v.y * (1.0f + erff(v.y * 0.70710678118654752440f)));
    o.z = f2b(0.5f * v.z * (1.0f + erff(v.z * 0.70710678118654752440f)));
    o.w = f2b(0.5f * v.w * (1.0f + erff(v.w * 0.70710678118654752440f)));
    *(ushort4*)(out + i4) = o;
}

// ---------------- transpose: src [R,C] (batched) -> dst bf16 [C,R] ----------------
template<bool SRC_F32>
__global__ __launch_bounds__(256) void transpose_kernel(const void* __restrict__ src,
                                                        ushort* __restrict__ dst,
                                                        int R, int C, long sS, long sD) {
    int z = blockIdx.z;
    const void* S = SRC_F32 ? (const void*)((const float*)src + (long)z * sS)
                            : (const void*)((const ushort*)src + (long)z * sS);
    ushort* D = dst + (long)z * sD;
    int r0 = blockIdx.y * 64, c0 = blockIdx.x * 64;
    __shared__ ushort T[64][68];
    int t = threadIdx.x;
#pragma unroll
    for (int p = 0; p < 4; p++) {
        int e = p * 256 + t;
        int row = e >> 4, cc = (e & 15) * 4;
        ushort4 v;
        if (SRC_F32) {
            float4 f = *(const float4*)((const float*)S + (long)(r0 + row) * C + c0 + cc);
            v.x = f2b(f.x); v.y = f2b(f.y); v.z = f2b(f.z); v.w = f2b(f.w);
        } else {
            v = *(const ushort4*)((const ushort*)S + (long)(r0 + row) * C + c0 + cc);
        }
        *(ushort4*)&T[row][cc] = v;
    }
    __syncthreads();
#pragma unroll
    for (int p = 0; p < 4; p++) {
        int e = p * 256 + t;
        int crow = e >> 4, rr = (e & 15) * 4;
        ushort4 o;
        o.x = T[rr + 0][crow]; o.y = T[rr + 1][crow];
        o.z = T[rr + 2][crow]; o.w = T[rr + 3][crow];
        *(ushort4*)&D[(long)(c0 + crow) * R + r0 + rr] = o;
    }
}

// ---------------- weight cast+transpose: Wt[n*K+k] = bf16(W[k*N+n]) ----------------
__global__ __launch_bounds__(256) void castT_kernel(const float* __restrict__ W,
                                                    ushort* __restrict__ Wt, int K, int N) {
    int k = blockIdx.x * 64 + (threadIdx.x & 63);
    int n = blockIdx.y * 4 + (threadIdx.x >> 6);
    Wt[(long)n * K + k] = f2b(W[(long)k * N + n]);
}

// ---------------- LayerNorm, one block per row of 768; fp32 or bf16 out ----------------
template<bool BF16OUT>
__global__ __launch_bounds__(256) void ln_kernel(const float* __restrict__ x,
                                                 const float* __restrict__ g,
                                                 const float* __restrict__ b,
                                                 void* __restrict__ outv) {
    int row = blockIdx.x;
    const float* xr = x + (long)row * NC;
    int t = threadIdx.x;
    float v0 = xr[t], v1 = xr[t + 256], v2 = xr[t + 512];
    float s = v0 + v1 + v2;
    float s2 = v0 * v0 + v1 * v1 + v2 * v2;
    for (int off = 32; off > 0; off >>= 1) {
        s  += __shfl_down(s, off, 64);
        s2 += __shfl_down(s2, off, 64);
    }
    __shared__ float ls[4], ls2[4];
    int wid = t >> 6, lane = t & 63;
    if (lane == 0) { ls[wid] = s; ls2[wid] = s2; }
    __syncthreads();
    if (t == 0) {
        float ts = ls[0] + ls[1] + ls[2] + ls[3];
        float ts2 = ls2[0] + ls2[1] + ls2[2] + ls2[3];
        float mu = ts * (1.0f / NC);
        float var = ts2 * (1.0f / NC) - mu * mu;
        ls[0] = mu;
        ls2[0] = 1.0f / sqrtf(var + 1e-6f);
    }
    __syncthreads();
    float mu = ls[0], r = ls2[0];
#pragma unroll
    for (int i = 0; i < 3; i++) {
        int c = t + i * 256;
        float vv = (i == 0 ? v0 : (i == 1 ? v1 : v2));
        float o = (vv - mu) * r * g[c] + b[c];
        if (BF16OUT) ((ushort*)outv)[(long)row * NC + c] = f2b(o);
        else         ((float*)outv)[(long)row * NC + c] = o;
    }
}

// ---------------- style vectors (fp32): s1[8,384] | s2[8,384] | ss[8,1536] ----------------
__global__ __launch_bounds__(256) void svec_kernel(const float* __restrict__ w,
                                                   const float* __restrict__ s1W, const float* __restrict__ s1b,
                                                   const float* __restrict__ s2W, const float* __restrict__ s2b,
                                                   const float* __restrict__ ssW, const float* __restrict__ ssb,
                                                   float* __restrict__ sout) {
    int gid = blockIdx.x * 256 + threadIdx.x;   // 0..18431
    int bb = gid / 2304;
    int r  = gid % 2304;
    const float* w0 = w + (long)bb * 1024;
    const float* w1 = w0 + 512;
    float acc = 0.f;
    if (r < 384) {
        for (int k = 0; k < 512; k++) acc += w0[k] * s1W[k * 384 + r];
        sout[bb * 384 + r] = acc + s1b[r];
    } else if (r < 768) {
        int c = r - 384;
        for (int k = 0; k < 512; k++) acc += w0[k] * s2W[k * 384 + c];
        sout[3072 + bb * 384 + c] = acc + s2b[c];
    } else {
        int c = r - 768;
        for (int k = 0; k < 512; k++) acc += w1[k] * ssW[k * 1536 + c];
        sout[6144 + bb * 1536 + c] = acc + ssb[c];
    }
}

extern "C" void kernel_launch(void* const* d_in, const int* in_sizes, int n_in,
                              void* d_out, int out_size, void* d_ws, size_t ws_size,
                              hipStream_t stream) {
    const float* x     = (const float*)d_in[0];
    const float* w     = (const float*)d_in[1];
    const float* ln1_g = (const float*)d_in[2];
    const float* ln1_b = (const float*)d_in[3];
    const float* ln2_g = (const float*)d_in[4];
    const float* ln2_b = (const float*)d_in[5];
    const float* g1_W  = (const float*)d_in[6];
    const float* g1_b  = (const float*)d_in[7];
    const float* s1_W  = (const float*)d_in[8];
    const float* s1_b  = (const float*)d_in[9];
    const float* m1_W  = (const float*)d_in[10];
    const float* m1_b  = (const float*)d_in[11];
    const float* g2_W  = (const float*)d_in[12];
    const float* g2_b  = (const float*)d_in[13];
    const float* s2_W  = (const float*)d_in[14];
    const float* s2_b  = (const float*)d_in[15];
    const float* m2_W  = (const float*)d_in[16];
    const float* m2_b  = (const float*)d_in[17];
    const float* gs_W  = (const float*)d_in[18];
    const float* gs_b  = (const float*)d_in[19];
    const float* ss_W  = (const float*)d_in[20];
    const float* ss_b  = (const float*)d_in[21];
    const float* ms_W  = (const float*)d_in[22];
    const float* ms_b  = (const float*)d_in[23];
    const float* r1_W  = (const float*)d_in[24];
    const float* r1_b  = (const float*)d_in[25];
    const float* r2_W  = (const float*)d_in[26];
    const float* r2_b  = (const float*)d_in[27];
    float* out = (float*)d_out;
    char* ws = (char*)d_ws;
    char* ob = (char*)d_out;

    // ---- ws layout (74,784,768 B; proven safe) ----
    float*  XLN = (float*)ws;                 // [16384,768] f32: xln -> x2 -> x3
    ushort* A1b = (ushort*)(ws + 50331648);   // 12.6 MB: a1 -> H1T -> AS chunks -> ar
    ushort* g1t = (ushort*)(ws + 62914560);   // W^T bf16 pool
    ushort* g2t = g1t + 589824;
    ushort* m1t = g2t + 589824;
    ushort* m2t = m1t + 147456;
    ushort* gst = m2t + 147456;
    ushort* mst = gst + 2359296;
    ushort* r1t = mst + 1179648;
    ushort* r2t = r1t + 589824;
    float*  SV  = (float*)(ws + 74711040);    // 18432 f32
    ushort* H1T = A1b;                        // [8,384,2048] alias
    ushort* ASq = A1b;                        // [4096,1536] chunk alias
    ushort* ARq = A1b;                        // [16384,384] alias

    // ---- d_out scratch phases ----
    ushort* XLNT  = (ushort*)(ob + 25165824); // p1: [8,768,2048] bf16 (T1 .. mix)
    ushort* A2q   = (ushort*)(ob + 12582912); // p1: a2 (dual-GLU .. h2)
    ushort* H2q   = (ushort*)ob;              // p1: h2 [16384,384] (h2 .. step8)
    ushort* H1q   = (ushort*)(ob + 12582912); // p1: h1 over a2 (h1 .. T2)
    float*  MIXTf = (float*)(ob + 12582912);  // p1: [8,768,384] f32 over h1 (mix)
    ushort* MIXTb = (ushort*)(ob + 25165824); // p1: bf16 over XLNT (gelu .. step8)
    ushort* X2LNq = (ushort*)(ob + 25165824); // p2: full ln2 [16384,768] bf16
    ushort* X3q   = (ushort*)ob;              // p2-3: x3 bf16 [16384,768]

    // 0. weight casts + style vectors + LN1 + T1
    castT_kernel<<<dim3(12, 192), 256, 0, stream>>>(g1_W, g1t, 768, 768);
    castT_kernel<<<dim3(12, 192), 256, 0, stream>>>(g2_W, g2t, 768, 768);
    castT_kernel<<<dim3(6,  96),  256, 0, stream>>>(m1_W, m1t, 384, 384);
    castT_kernel<<<dim3(6,  96),  256, 0, stream>>>(m2_W, m2t, 384, 384);
    castT_kernel<<<dim3(12, 768), 256, 0, stream>>>(gs_W, gst, 768, 3072);
    castT_kernel<<<dim3(24, 192), 256, 0, stream>>>(ms_W, mst, 1536, 768);
    castT_kernel<<<dim3(12, 192), 256, 0, stream>>>(r1_W, r1t, 768, 768);
    castT_kernel<<<dim3(6,  192), 256, 0, stream>>>(r2_W, r2t, 384, 768);
    svec_kernel<<<72, 256, 0, stream>>>(w, s1_W, s1_b, s2_W, s2_b, ss_W, ss_b, SV);
    ln_kernel<false><<<ROWS, 256, 0, stream>>>(x, ln1_g, ln1_b, XLN);
    transpose_kernel<true><<<dim3(12, 32, NB), 256, 0, stream>>>(
        XLN, XLNT, 2048, 768, (long)2048 * 768, (long)768 * 2048);

    // 3+5. merged dual-GLU: a1 -> A1b, a2 -> A2q   (768 blocks)
    gemm_glu_mfma<128, true, true><<<dim3(3, 128, 2), 256, 0, stream>>>(
        XLN, g1t, g2t, A1b, A2q, ROWS, 384, 768, 768, g1_b, g2_b, SV, SV + 3072, 0);
    // 6. h2 = a2@m2 -> H2q   (768 blocks)
    gemm_mfma<64, 0, true, false><<<dim3(6, 128), 256, 0, stream>>>(
        A2q, m2t, nullptr, H2q, ROWS, 384, 384, 384, 384, 384, 0, 0, 0, m2_b);
    // 4. h1 = a1@m1 -> H1q (over dead a2)
    gemm_mfma<64, 0, true, false><<<dim3(6, 128), 256, 0, stream>>>(
        A1b, m1t, nullptr, H1q, ROWS, 384, 384, 384, 384, 384, 0, 0, 0, m1_b);
    // T2: H1T = h1^T -> A1b (a1 dead)
    transpose_kernel<false><<<dim3(6, 32, NB), 256, 0, stream>>>(
        H1q, H1T, 2048, 384, (long)2048 * 384, (long)384 * 2048);
    // 7. mixT(f32) += xlnT@h1T, split-K x4, atomic  (576 blocks)
    hipMemsetAsync(MIXTf, 0, (size_t)NB * 768 * 384 * 4, stream);
    gemm_mfma<128, 6, false, true><<<dim3(3, 6, NB * 4), 256, 0, stream>>>(
        XLNT, H1T, MIXTf, nullptr, 768, 384, 2048, 2048, 2048, 384,
        (long)768 * 2048, (long)384 * 2048, (long)768 * 384, nullptr);
    // gelu + cast -> MIXTb (over dead XLNT)
    gelu_cast_kernel<<<2304, 256, 0, stream>>>(MIXTf, MIXTb);
    // 8. x2 = xln + h2@mixT^T (f32 in-place)   (768 blocks)
    gemm_mfma<128, 3, false, false><<<dim3(6, 16, NB), 256, 0, stream>>>(
        H2q, MIXTb, XLN, nullptr, 2048, 768, 384, 384, 384, 768,
        (long)2048 * 384, (long)768 * 384, (long)2048 * 768, nullptr);
    // 9. full LN2 -> X2LNq bf16
    ln_kernel<true><<<ROWS, 256, 0, stream>>>(XLN, ln2_g, ln2_b, X2LNq);
    // 10-11. style branch, 4 chunks of 4096 rows (AS buffer = A1b, 12.6 MB)
    for (int ch = 0; ch < 4; ch++) {
        ushort* X2c = X2LNq + (long)ch * 4096 * 768;
        float*  XLNc = XLN + (long)ch * 4096 * 768;
        ushort* X3c = X3q + (long)ch * 4096 * 768;
        gemm_glu_mfma<64, true, false><<<dim3(24, 32), 256, 0, stream>>>(
            X2c, gst, gst, ASq, ASq, 4096, 1536, 768, 768, gs_b, gs_b,
            SV + 6144, SV + 6144, ch * 2);
        gemm_mfma<64, 4, true, false><<<dim3(12, 32), 256, 0, stream>>>(
            ASq, mst, XLNc, X3c, 4096, 768, 1536, 1536, 1536, 768, 0, 0, 0, ms_b);
    }
    // 12. ar = glu(x3@r1_W) -> ARq   (768 blocks)
    gemm_glu_mfma<64, false, false><<<dim3(6, 128), 256, 0, stream>>>(
        X3q, r1t, r1t, ARq, ARq, ROWS, 384, 768, 768, r1_b, r1_b, nullptr, nullptr, 0);
    // 13. out = ar@r2_W + r2_b (fp32 final, overwrites all d_out scratch)
    gemm_mfma<128, 5, true, false><<<dim3(6, 128), 256, 0, stream>>>(
        ARq, r2t, out, nullptr, ROWS, 768, 384, 384, 384, 768, 0, 0, 0, r2_b);
}